// Round 7
// baseline (930.591 us; speedup 1.0000x reference)
//
#include <hip/hip_runtime.h>
#include <stdint.h>

#define B_DIM 512
#define I_DIM 128
#define H_DIM 128
#define G_DIM 384
#define STEPS 511   // reference scans t = 0..T-2

typedef __attribute__((ext_vector_type(8))) short bf16x8;
typedef __attribute__((ext_vector_type(4))) float f32x4;
typedef _Float16 half2_t __attribute__((ext_vector_type(2)));

__device__ __forceinline__ unsigned bf16rne(float f) {
  unsigned u = __float_as_uint(f);
  return (u + 0x7fffu + ((u >> 16) & 1u)) >> 16;
}
__device__ __forceinline__ short bf16s(float f) { return (short)bf16rne(f); }

// Guaranteed single-instruction packed fma (v_pk_fma_f16).
__device__ __forceinline__ half2_t pk_fma(half2_t a, half2_t b, half2_t c) {
#if __has_builtin(__builtin_elementwise_fma)
  return __builtin_elementwise_fma(a, b, c);
#else
  half2_t d;
  asm("v_pk_fma_f16 %0, %1, %2, %3" : "=v"(d) : "v"(a), "v"(b), "v"(c));
  return d;
#endif
}

// Barrier draining ONLY LDS ops; global prefetches stay in flight across it.
#define BAR_LDS() asm volatile("s_waitcnt lgkmcnt(0)\n\ts_barrier" ::: "memory")

// ---------------------------------------------------------------------------
// Kernel A (MFMA): xp[row][g] = x[row][:].Wih[g][:] + bih[g] (+bhh[g] folded
// for the r,z gate thirds). fp16 output. Unchanged from round 6 (verified).
// ---------------------------------------------------------------------------
__global__ __launch_bounds__(512, 2) void k_xproj(
    const float* __restrict__ xch, const float* __restrict__ Wih,
    const float* __restrict__ bih, const float* __restrict__ bhh,
    _Float16* __restrict__ xp) {
  __shared__ __align__(16) char As[128 * 256];  // 32 KB bf16 A tile
  const int tid = threadIdx.x;
  const int lane = tid & 63;
  const int wave = tid >> 6;
  const int mh = wave & 1, nh = wave >> 1;
  const int l15 = lane & 15, l4 = lane >> 4;

  const float4* xs = (const float4*)(xch + (size_t)blockIdx.x * 128 * I_DIM);
#pragma unroll
  for (int q = 0; q < 8; ++q) {
    const int fi = tid + 512 * q;
    const int row = fi >> 5, kq = fi & 31;
    const float4 v = xs[fi];
    uint2 p;
    p.x = bf16rne(v.x) | (bf16rne(v.y) << 16);
    p.y = bf16rne(v.z) | (bf16rne(v.w) << 16);
    *(uint2*)(As + (row << 8) + ((kq << 3) ^ ((row & 7) << 4))) = p;
  }

  bf16x8 bf[6][4];
  float bv[6];
#pragma unroll
  for (int nf = 0; nf < 6; ++nf) {
    const int col = nh * 96 + nf * 16 + l15;
    bv[nf] = bih[col] + (col < 256 ? bhh[col] : 0.f);
#pragma unroll
    for (int ks = 0; ks < 4; ++ks) {
      const float* wr = Wih + (size_t)col * I_DIM + ks * 32 + l4 * 8;
      const float4 wa = *(const float4*)wr;
      const float4 wb = *(const float4*)(wr + 4);
      bf16x8 b;
      b[0] = bf16s(wa.x); b[1] = bf16s(wa.y); b[2] = bf16s(wa.z); b[3] = bf16s(wa.w);
      b[4] = bf16s(wb.x); b[5] = bf16s(wb.y); b[6] = bf16s(wb.z); b[7] = bf16s(wb.w);
      bf[nf][ks] = b;
    }
  }
  __syncthreads();

  f32x4 acc[4][6];
#pragma unroll
  for (int m = 0; m < 4; ++m)
#pragma unroll
    for (int nf = 0; nf < 6; ++nf) acc[m][nf] = (f32x4){0.f, 0.f, 0.f, 0.f};

#pragma unroll
  for (int ks = 0; ks < 4; ++ks) {
#pragma unroll
    for (int m = 0; m < 4; ++m) {
      const int arow = mh * 64 + m * 16 + l15;
      const int kbyte = ks * 64 + l4 * 16;
      const bf16x8 a =
          *(const bf16x8*)(As + (arow << 8) + (kbyte ^ ((arow & 7) << 4)));
#pragma unroll
      for (int nf = 0; nf < 6; ++nf)
        acc[m][nf] =
            __builtin_amdgcn_mfma_f32_16x16x32_bf16(a, bf[nf][ks], acc[m][nf], 0, 0, 0);
    }
  }

#pragma unroll
  for (int m = 0; m < 4; ++m) {
    const size_t row0 = (size_t)blockIdx.x * 128 + mh * 64 + m * 16 + l4 * 4;
#pragma unroll
    for (int nf = 0; nf < 6; ++nf) {
      const int col = nh * 96 + nf * 16 + l15;
#pragma unroll
      for (int r = 0; r < 4; ++r)
        xp[(row0 + r) * G_DIM + col] = (_Float16)(acc[m][nf][r] + bv[nf]);
    }
  }
}

// ---------------------------------------------------------------------------
// Kernel B: GRU recurrence, one barrier/step. 512 blocks x 1 row, 128 thr
// (2 waves). Thread = unit j, full K=128 in 192 weight VGPRs. This round:
//  - pk_fma forced (v_pk_fma_f16), 6 accumulators (2/gate, 32-deep chains)
//  - all 16 h ds_read_b128 hoisted into hr[16] before any FMA
//  - decode shfl chain placed between phase A and phase B
//  - h written per-thread ds_write_b16 (no pack shfl)
// ---------------------------------------------------------------------------
__global__ __launch_bounds__(128, 1) void k_rec(
    const _Float16* __restrict__ xp, const float* __restrict__ gt,
    const float* __restrict__ Whh, const float* __restrict__ bhh,
    const float* __restrict__ Wdec, const float* __restrict__ bdec,
    float* __restrict__ ws_h, float* __restrict__ nll_part,
    int t0, int t1, int first) {
  __shared__ __align__(16) _Float16 hbuf[2][H_DIM];  // double-buffered f16 h
  __shared__ float dw[2][2];                         // decode partial ring

  const int tid = threadIdx.x;   // unit j
  const int lane = tid & 63;
  const int wv = tid >> 6;
  const int row = blockIdx.x;

  // ---- one-time: full-K weight rows for unit tid, f16-packed ----
  half2_t w0[64], w1[64], w2[64];
  {
    const float4* p0 = (const float4*)(Whh + (size_t)tid * H_DIM);
    const float4* p1 = (const float4*)(Whh + (size_t)(H_DIM + tid) * H_DIM);
    const float4* p2 = (const float4*)(Whh + (size_t)(2 * H_DIM + tid) * H_DIM);
#pragma unroll
    for (int c = 0; c < 32; ++c) {
      float4 v;
      v = p0[c];
      w0[2 * c]     = (half2_t){(_Float16)v.x, (_Float16)v.y};
      w0[2 * c + 1] = (half2_t){(_Float16)v.z, (_Float16)v.w};
      v = p1[c];
      w1[2 * c]     = (half2_t){(_Float16)v.x, (_Float16)v.y};
      w1[2 * c + 1] = (half2_t){(_Float16)v.z, (_Float16)v.w};
      v = p2[c];
      w2[2 * c]     = (half2_t){(_Float16)v.x, (_Float16)v.y};
      w2[2 * c + 1] = (half2_t){(_Float16)v.z, (_Float16)v.w};
    }
  }
  const float bhn = bhh[2 * H_DIM + tid];
  const float wdj = Wdec[tid];
  const float bd0 = bdec[0];

  float h_old = first ? 0.f : ws_h[(size_t)row * H_DIM + tid];
  hbuf[t0 & 1][tid] = (_Float16)h_old;

  // first step's xp
  _Float16 xr_c, xz_c, xn_c;
  {
    const size_t b = (size_t)row * G_DIM;
    xr_c = xp[b + tid];
    xz_c = xp[b + H_DIM + tid];
    xn_c = xp[b + 2 * H_DIM + tid];
  }
  float nll0 = 0.f, g_old = 0.f, g_mid = 0.f, pv = 0.f;
  __syncthreads();

#pragma unroll 1
  for (int s = t0; s < t1; ++s) {
    // prefetch next step's xp (branchless clamp; in flight across barrier)
    const int nidx = (s + 1 < t1 ? s + 1 : t1 - 1) - t0;
    const size_t b = ((size_t)nidx * B_DIM + row) * G_DIM;
    const _Float16 xr_n = xp[b + tid];
    const _Float16 xz_n = xp[b + H_DIM + tid];
    const _Float16 xn_n = xp[b + 2 * H_DIM + tid];
    if (tid == 0) {
      // NLL for step s-2 (dw slot (s-2)&1 == s&1, written mid-step s-1)
      if (s >= t0 + 2) {
        const float v = dw[s & 1][0] + dw[s & 1][1];
        const float C = 1.f / (1.f + __expf(-(v + bd0)));
        nll0 -= g_old * __logf(C + 1e-4f) +
                (1.f - g_old) * __logf(1.f - C + 1e-4f);
      }
      g_old = g_mid;
      g_mid = gt[(size_t)(s + 1) * B_DIM + row];
    }

    // ---- phase A: hoisted h loads, then 192 v_pk_fma_f16 (6 chains) ----
    uint4 hr[16];
    {
      const uint4* hb = (const uint4*)hbuf[s & 1];
#pragma unroll
      for (int c = 0; c < 16; ++c) hr[c] = hb[c];  // 16 batched b128 reads
    }
    half2_t ar0 = (half2_t){0, 0}, ar1 = (half2_t){0, 0};
    half2_t az0 = (half2_t){0, 0}, az1 = (half2_t){0, 0};
    half2_t an0 = (half2_t){0, 0}, an1 = (half2_t){0, 0};
#pragma unroll
    for (int c = 0; c < 16; ++c) {
      const half2_t h0 = __builtin_bit_cast(half2_t, hr[c].x);
      const half2_t h1 = __builtin_bit_cast(half2_t, hr[c].y);
      const half2_t h2 = __builtin_bit_cast(half2_t, hr[c].z);
      const half2_t h3 = __builtin_bit_cast(half2_t, hr[c].w);
      ar0 = pk_fma(h0, w0[4 * c], ar0);     az0 = pk_fma(h0, w1[4 * c], az0);     an0 = pk_fma(h0, w2[4 * c], an0);
      ar1 = pk_fma(h1, w0[4 * c + 1], ar1); az1 = pk_fma(h1, w1[4 * c + 1], az1); an1 = pk_fma(h1, w2[4 * c + 1], an1);
      ar0 = pk_fma(h2, w0[4 * c + 2], ar0); az0 = pk_fma(h2, w1[4 * c + 2], az0); an0 = pk_fma(h2, w2[4 * c + 2], an0);
      ar1 = pk_fma(h3, w0[4 * c + 3], ar1); az1 = pk_fma(h3, w1[4 * c + 3], az1); an1 = pk_fma(h3, w2[4 * c + 3], an1);
    }

    // decode shfl-reduce for step s-1 (independent; latency hides under
    // the gate math below)
    if (s > t0) {
      float v = pv;
#pragma unroll
      for (int off = 32; off; off >>= 1) v += __shfl_down(v, off);
      if (lane == 0) dw[(s - 1) & 1][wv] = v;
    }

    // ---- phase B: gate math, same thread (no exchange) ----
    const float rp = (float)ar0.x + (float)ar0.y + (float)ar1.x +
                     (float)ar1.y + (float)xr_c;  // bhh_r folded into xp
    const float zp = (float)az0.x + (float)az0.y + (float)az1.x +
                     (float)az1.y + (float)xz_c;
    const float hn = (float)an0.x + (float)an0.y + (float)an1.x +
                     (float)an1.y + bhn;
    const float r_ = 1.f / (1.f + __expf(-rp));
    const float z_ = 1.f / (1.f + __expf(-zp));
    const float e2 = __expf(2.f * ((float)xn_c + r_ * hn));
    const float n_ = 1.f - 2.f / (e2 + 1.f);
    const float hnew = (1.f - z_) * n_ + z_ * h_old;
    h_old = hnew;
    hbuf[(s + 1) & 1][tid] = (_Float16)hnew;  // ds_write_b16, conflict-free
    pv = hnew * wdj;
    xr_c = xr_n; xz_c = xz_n; xn_c = xn_n;
    BAR_LDS();  // the ONE barrier: h(s+1) + dw published
  }

  // ---- epilogue: flush the 2-deep NLL pipeline ----
  {
    float v = pv;  // decode for step t1-1
#pragma unroll
    for (int off = 32; off; off >>= 1) v += __shfl_down(v, off);
    if (lane == 0) dw[(t1 - 1) & 1][wv] = v;
    if (tid == 0 && t1 - t0 >= 2) {  // NLL(t1-2): slot (t1-2)&1 == t1&1
      const float vv = dw[t1 & 1][0] + dw[t1 & 1][1];
      const float C = 1.f / (1.f + __expf(-(vv + bd0)));
      nll0 -= g_old * __logf(C + 1e-4f) +
              (1.f - g_old) * __logf(1.f - C + 1e-4f);
    }
    BAR_LDS();
    if (tid == 0) {  // NLL(t1-1), gt[t1] = g_mid
      const float vv = dw[(t1 - 1) & 1][0] + dw[(t1 - 1) & 1][1];
      const float C = 1.f / (1.f + __expf(-(vv + bd0)));
      nll0 -= g_mid * __logf(C + 1e-4f) +
              (1.f - g_mid) * __logf(1.f - C + 1e-4f);
      nll_part[row] = first ? nll0 : (nll_part[row] + nll0);
    }
  }
  ws_h[(size_t)row * H_DIM + tid] = h_old;
}

// ---------------------------------------------------------------------------
__global__ __launch_bounds__(512) void k_fin(const float* __restrict__ nll_part,
                                             float* __restrict__ out) {
  __shared__ float red[8];
  const int tid = threadIdx.x;
  float v = nll_part[tid];
#pragma unroll
  for (int off = 32; off; off >>= 1) v += __shfl_down(v, off);
  if ((tid & 63) == 0) red[tid >> 6] = v;
  __syncthreads();
  if (tid == 0) {
    float s = 0.f;
#pragma unroll
    for (int i = 0; i < 8; ++i) s += red[i];
    out[0] = s * (1.f / (512.f * 512.f));
  }
}

// ---------------------------------------------------------------------------
extern "C" void kernel_launch(void* const* d_in, const int* in_sizes, int n_in,
                              void* d_out, int out_size, void* d_ws,
                              size_t ws_size, hipStream_t stream) {
  const float* x    = (const float*)d_in[0];
  const float* gt   = (const float*)d_in[1];
  const float* Wih  = (const float*)d_in[2];
  const float* Whh  = (const float*)d_in[3];
  const float* bih  = (const float*)d_in[4];
  const float* bhh  = (const float*)d_in[5];
  const float* Wdec = (const float*)d_in[6];
  const float* bdec = (const float*)d_in[7];

  // ws layout: [0,2KB) nll_part[512]; [4KB,260KB) h state; then xp chunk
  float* nll_part = (float*)d_ws;
  float* ws_h = (float*)((char*)d_ws + 4096);
  const size_t xp_off = 4096 + (size_t)B_DIM * H_DIM * 4;  // 266240
  _Float16* xp = (_Float16*)((char*)d_ws + xp_off);

  const size_t chunk_bytes = (size_t)B_DIM * G_DIM * 2;  // fp16 per timestep
  size_t avail = ws_size > xp_off ? ws_size - xp_off : 0;
  int Tc = (int)(avail / chunk_bytes);
  if (Tc > 128) Tc = 128;      // xp chunk <=50 MB, L3-resident
  if (Tc < 1) Tc = 1;

  for (int t0 = 0; t0 < STEPS; t0 += Tc) {
    int t1 = t0 + Tc;
    if (t1 > STEPS) t1 = STEPS;
    const int nt = t1 - t0;
    k_xproj<<<dim3(nt * 4), dim3(512), 0, stream>>>(
        x + (size_t)t0 * B_DIM * I_DIM, Wih, bih, bhh, xp);
    k_rec<<<dim3(512), dim3(128), 0, stream>>>(
        xp, gt, Whh, bhh, Wdec, bdec, ws_h, nll_part, t0, t1, t0 == 0 ? 1 : 0);
  }
  k_fin<<<dim3(1), dim3(512), 0, stream>>>(nll_part, (float*)d_out);
}